// Round 6
// baseline (10200.104 us; speedup 1.0000x reference)
//
#include <hip/hip_runtime.h>
#include <hip/hip_cooperative_groups.h>
#include <math.h>

namespace cg = cooperative_groups;

#define B 64
#define P 196
#define E 2048
#define D 256
#define H_ 256
#define EM 256
#define V 10000
#define L 32
#define T 31
#define KX 2560   // EM + E + D

struct Params {
    const float* feat; const int* tok; const int* clen;
    const float* Wf; const float* bf; const float* Wh; const float* bh;
    const float* We; const float* be; const float* emb;
    const float* W_ih; const float* b_ih; const float* W_hh; const float* b_hh;
    const float* W_hid; const float* b_hid; const float* W_cell; const float* b_cell;
    const float* W_gate; const float* b_gate; const float* W_head; const float* b_head;
    float* out1; float* out2;
    int* order; int* target;
    float* fe; float* h; float* c; float* wbuf; float* xbuf;
    float* gpart; float* mean_feat; float* hpart; float* hn_all;
};

// ---------- fe tile: 64 rows x 128 cols, BK=32 (LDS: 6336 floats) ----------
__device__ __forceinline__ void fe_tile(const Params& p, int task, int tid, float* sm) {
    float* As = sm;                       // [32][68]
    float* Bs = sm + 2176;                // [32][128]
    int* srcRow = (int*)(sm + 6272);      // 64 ints
    int rb = task >> 1, cb = task & 1;
    __syncthreads();
    if (tid < 64) {
        int gr = rb * 64 + tid;
        int b = gr / P, pp = gr % P;
        srcRow[tid] = p.order[b] * P + pp;
    }
    __syncthreads();
    int tx = tid & 15, ty = tid >> 4;
    float acc[4][8] = {};
    for (int k0 = 0; k0 < E; k0 += 32) {
        #pragma unroll
        for (int q = 0; q < 2; ++q) {
            int idx = q * 256 + tid;
            int kv = idx & 7, m = idx >> 3;
            float4 v = *(const float4*)(p.feat + (size_t)srcRow[m] * E + k0 + kv * 4);
            As[(kv*4+0)*68+m] = v.x; As[(kv*4+1)*68+m] = v.y;
            As[(kv*4+2)*68+m] = v.z; As[(kv*4+3)*68+m] = v.w;
        }
        #pragma unroll
        for (int q = 0; q < 4; ++q) {
            int idx = q * 256 + tid;
            int n4 = idx & 31, kk = idx >> 5;
            float4 v = *(const float4*)(p.Wf + (size_t)(k0+kk)*H_ + cb*128 + n4*4);
            *(float4*)&Bs[kk*128 + n4*4] = v;
        }
        __syncthreads();
        #pragma unroll
        for (int kk = 0; kk < 32; ++kk) {
            float4 av = *(const float4*)&As[kk*68 + ty*4];
            float4 b0 = *(const float4*)&Bs[kk*128 + tx*8];
            float4 b1 = *(const float4*)&Bs[kk*128 + tx*8 + 4];
            float a_[4] = {av.x, av.y, av.z, av.w};
            float b_[8] = {b0.x,b0.y,b0.z,b0.w,b1.x,b1.y,b1.z,b1.w};
            #pragma unroll
            for (int r = 0; r < 4; ++r)
                #pragma unroll
                for (int cc = 0; cc < 8; ++cc)
                    acc[r][cc] += a_[r] * b_[cc];
        }
        __syncthreads();
    }
    float4 bias0 = *(const float4*)(p.bf + cb*128 + tx*8);
    float4 bias1 = *(const float4*)(p.bf + cb*128 + tx*8 + 4);
    #pragma unroll
    for (int r = 0; r < 4; ++r) {
        int gr = rb * 64 + ty * 4 + r;
        float4 o0 = {acc[r][0]+bias0.x, acc[r][1]+bias0.y, acc[r][2]+bias0.z, acc[r][3]+bias0.w};
        float4 o1 = {acc[r][4]+bias1.x, acc[r][5]+bias1.y, acc[r][6]+bias1.z, acc[r][7]+bias1.w};
        *(float4*)(p.fe + (size_t)gr * H_ + cb*128 + tx*8) = o0;
        *(float4*)(p.fe + (size_t)gr * H_ + cb*128 + tx*8 + 4) = o1;
    }
}

// ---------- h0c0 split-K tile (LDS: 4224 floats) ----------
__device__ __forceinline__ void h0c0_tile(const Params& p, int task, int tid, float* sm) {
    float* As = sm;            // [32][68]
    float* Bs = sm + 2176;     // [32][64]
    int cb = task >> 3, ky = task & 7;
    const float* Wsrc; int ncol0;
    if (cb < 4) { Wsrc = p.W_hid;  ncol0 = cb * 64; }
    else        { Wsrc = p.W_cell; ncol0 = (cb - 4) * 64; }
    int tx = tid & 15, ty = tid >> 4;
    float acc[4][4] = {};
    __syncthreads();
    for (int k0 = ky * 256; k0 < ky * 256 + 256; k0 += 32) {
        #pragma unroll
        for (int q = 0; q < 2; ++q) {
            int idx = q * 256 + tid;
            int kv = idx & 7, m = idx >> 3;
            float4 v = *(const float4*)(p.mean_feat + (size_t)m * E + k0 + kv * 4);
            As[(kv*4+0)*68+m] = v.x; As[(kv*4+1)*68+m] = v.y;
            As[(kv*4+2)*68+m] = v.z; As[(kv*4+3)*68+m] = v.w;
        }
        #pragma unroll
        for (int q = 0; q < 2; ++q) {
            int idx = q * 256 + tid;
            int n4 = idx & 15, kk = idx >> 4;
            float4 v = *(const float4*)(Wsrc + (size_t)(k0 + kk) * 256 + ncol0 + n4 * 4);
            *(float4*)&Bs[kk*64 + n4*4] = v;
        }
        __syncthreads();
        #pragma unroll
        for (int kk = 0; kk < 32; ++kk) {
            float4 av = *(const float4*)&As[kk*68 + ty*4];
            float4 bv = *(const float4*)&Bs[kk*64 + tx*4];
            acc[0][0] += av.x*bv.x; acc[0][1] += av.x*bv.y; acc[0][2] += av.x*bv.z; acc[0][3] += av.x*bv.w;
            acc[1][0] += av.y*bv.x; acc[1][1] += av.y*bv.y; acc[1][2] += av.y*bv.z; acc[1][3] += av.y*bv.w;
            acc[2][0] += av.z*bv.x; acc[2][1] += av.z*bv.y; acc[2][2] += av.z*bv.z; acc[2][3] += av.z*bv.w;
            acc[3][0] += av.w*bv.x; acc[3][1] += av.w*bv.y; acc[3][2] += av.w*bv.z; acc[3][3] += av.w*bv.w;
        }
        __syncthreads();
    }
    #pragma unroll
    for (int a = 0; a < 4; ++a) {
        int row = ty * 4 + a;
        float4 o = {acc[a][0], acc[a][1], acc[a][2], acc[a][3]};
        *(float4*)(p.hpart + ((size_t)ky * B + row) * 512 + cb * 64 + tx * 4) = o;
    }
}

// ---------- h0c0 reduce ----------
__device__ __forceinline__ void reduce_task(const Params& p, int b, int tid) {
    float s0 = 0.f, s1 = 0.f;
    #pragma unroll
    for (int ky = 0; ky < 8; ++ky) {
        const float* hp = p.hpart + ((size_t)ky * B + b) * 512;
        s0 += hp[tid]; s1 += hp[256 + tid];
    }
    float h0 = s0 + p.b_hid[tid];
    p.h[b * D + tid] = h0;
    p.c[b * D + tid] = s1 + p.b_cell[tid];
    p.xbuf[(size_t)b * KX + 2304 + tid] = h0;
    int tok0 = p.tok[p.order[b] * L + 0];
    p.xbuf[(size_t)b * KX + tid] = p.emb[(size_t)tok0 * EM + tid];
}

// ---------- fused LSTM pointwise (step t-1) + attention (step t) ----------
__device__ __forceinline__ void attn_pw_phase(const Params& p, int t, int b, int tid, float* sm) {
    float* hs  = sm;
    float* hes = sm + 256;
    float* es  = sm + 512;   // 196
    float* red = sm + 712;   // 4
    int tgt = p.target[b];
    bool pw_active = (t > 0) && (tgt > t - 1);
    bool at_active = (tgt > t);
    if (!pw_active && !at_active) return;
    __syncthreads();
    if (pw_active) {
        int d = tid;
        float gi = p.b_ih[d] + p.b_hh[d];
        float gf = p.b_ih[D + d] + p.b_hh[D + d];
        float gg = p.b_ih[2 * D + d] + p.b_hh[2 * D + d];
        float go = p.b_ih[3 * D + d] + p.b_hh[3 * D + d];
        #pragma unroll
        for (int ky = 0; ky < 8; ++ky) {
            const float* gp = p.gpart + ((size_t)ky * B + b) * 1024;
            gi += gp[d]; gf += gp[D + d]; gg += gp[2 * D + d]; go += gp[3 * D + d];
        }
        float c_old = p.c[b * D + d];
        float si = 1.f / (1.f + expf(-gi));
        float sf = 1.f / (1.f + expf(-gf));
        float so = 1.f / (1.f + expf(-go));
        float cn = sf * c_old + si * tanhf(gg);
        float hnv = so * tanhf(cn);
        p.c[b * D + d] = cn;
        p.h[b * D + d] = hnv;
        hs[d] = hnv;
        p.hn_all[((size_t)(t - 1) * B + b) * D + d] = hnv;
        p.xbuf[(size_t)b * KX + 2304 + d] = hnv;
        int tokn = p.tok[p.order[b] * L + t];
        p.xbuf[(size_t)b * KX + d] = p.emb[(size_t)tokn * EM + d];
    } else {
        hs[tid] = p.h[b * D + tid];
    }
    __syncthreads();
    if (!at_active) return;
    float acc = 0.f;
    #pragma unroll 8
    for (int k = 0; k < D; ++k) acc += hs[k] * p.Wh[(size_t)k * H_ + tid];
    hes[tid] = acc + p.bh[tid];
    __syncthreads();
    int wave = tid >> 6, lane = tid & 63;
    float4 he4 = *(const float4*)&hes[lane * 4];
    float4 we4 = *(const float4*)(p.We + lane * 4);
    for (int pp = wave; pp < P; pp += 4) {
        float4 fv = *(const float4*)(p.fe + ((size_t)b * P + pp) * H_ + lane * 4);
        float x0 = fv.x + he4.x; x0 = x0 > 0.f ? x0 : 0.f;
        float x1 = fv.y + he4.y; x1 = x1 > 0.f ? x1 : 0.f;
        float x2 = fv.z + he4.z; x2 = x2 > 0.f ? x2 : 0.f;
        float x3 = fv.w + he4.w; x3 = x3 > 0.f ? x3 : 0.f;
        float s = x0 * we4.x + x1 * we4.y + x2 * we4.z + x3 * we4.w;
        #pragma unroll
        for (int off = 32; off > 0; off >>= 1) s += __shfl_down(s, off);
        if (lane == 0) es[pp] = s + p.be[0];
    }
    __syncthreads();
    float mx = -1e30f;
    for (int pp = tid; pp < P; pp += 256) mx = fmaxf(mx, es[pp]);
    #pragma unroll
    for (int off = 32; off > 0; off >>= 1) mx = fmaxf(mx, __shfl_down(mx, off));
    if (lane == 0) red[wave] = mx;
    __syncthreads();
    mx = fmaxf(fmaxf(red[0], red[1]), fmaxf(red[2], red[3]));
    __syncthreads();
    float sum = 0.f;
    for (int pp = tid; pp < P; pp += 256) {
        float ex = expf(es[pp] - mx);
        es[pp] = ex;
        sum += ex;
    }
    #pragma unroll
    for (int off = 32; off > 0; off >>= 1) sum += __shfl_down(sum, off);
    if (lane == 0) red[wave] = sum;
    __syncthreads();
    sum = red[0] + red[1] + red[2] + red[3];
    float inv = 1.0f / sum;
    for (int pp = tid; pp < P; pp += 256) {
        float wv = es[pp] * inv;
        p.wbuf[b * P + pp] = wv;
        p.out2[((size_t)b * T + t) * P + pp] = wv;
    }
}

// ---------- ctx + gate -> xbuf (LDS: ~2000 floats) ----------
__device__ __forceinline__ void ctx_phase(const Params& p, int t, int b, int y, int tid, float* sm) {
    if (p.target[b] <= t) return;
    float* ws_ = sm;                       // 196
    float* hs  = sm + 196;                 // 256
    float4* rc = (float4*)(sm + 464);      // 3*64 float4
    float4* rg = (float4*)(sm + 464 + 768);
    __syncthreads();
    if (tid < P) ws_[tid] = p.wbuf[b * P + tid];
    hs[tid] = p.h[b * D + tid];
    __syncthreads();
    int c4 = tid & 63, q = tid >> 6;
    int src = p.order[b];
    const float4* f4 = (const float4*)(p.feat + (size_t)src * P * E) + y * 64 + c4;
    float4 acc = {0.f, 0.f, 0.f, 0.f};
    for (int pp = q * 49; pp < q * 49 + 49; ++pp) {
        float w = ws_[pp];
        float4 fv = f4[(size_t)pp * 512];
        acc.x += w * fv.x; acc.y += w * fv.y; acc.z += w * fv.z; acc.w += w * fv.w;
    }
    const float4* g4 = (const float4*)p.W_gate + y * 64 + c4;
    float4 gacc = {0.f, 0.f, 0.f, 0.f};
    for (int k = q * 64; k < q * 64 + 64; ++k) {
        float hv = hs[k];
        float4 wv = g4[(size_t)k * 512];
        gacc.x += hv * wv.x; gacc.y += hv * wv.y; gacc.z += hv * wv.z; gacc.w += hv * wv.w;
    }
    if (q) { rc[(q - 1) * 64 + c4] = acc; rg[(q - 1) * 64 + c4] = gacc; }
    __syncthreads();
    if (q == 0) {
        #pragma unroll
        for (int j = 0; j < 3; ++j) {
            float4 a = rc[j * 64 + c4], g = rg[j * 64 + c4];
            acc.x += a.x; acc.y += a.y; acc.z += a.z; acc.w += a.w;
            gacc.x += g.x; gacc.y += g.y; gacc.z += g.z; gacc.w += g.w;
        }
        float4 gb = *(const float4*)(p.b_gate + (y * 64 + c4) * 4);
        float4 o;
        o.x = acc.x / (1.f + expf(-(gacc.x + gb.x)));
        o.y = acc.y / (1.f + expf(-(gacc.y + gb.y)));
        o.z = acc.z / (1.f + expf(-(gacc.z + gb.z)));
        o.w = acc.w / (1.f + expf(-(gacc.w + gb.w)));
        *(float4*)(p.xbuf + (size_t)b * KX + EM + (y * 64 + c4) * 4) = o;
    }
}

// ---------- gate GEMM tile (cb 0..15, ky 0..7; LDS: 4224 floats) ----------
__device__ __forceinline__ void lstm_tile(const Params& p, int cb, int ky, int tid, float* sm) {
    float* As = sm;            // [32][68]
    float* Bs = sm + 2176;     // [32][64]
    int tx = tid & 15, ty = tid >> 4;
    float acc[4][4] = {};
    int k0base = ky * 320;
    __syncthreads();
    for (int k0 = k0base; k0 < k0base + 320; k0 += 32) {
        #pragma unroll
        for (int q = 0; q < 2; ++q) {
            int idx = q * 256 + tid;
            int kv = idx & 7, m = idx >> 3;
            float4 v = *(const float4*)(p.xbuf + (size_t)m * KX + k0 + kv * 4);
            As[(kv*4+0)*68+m] = v.x; As[(kv*4+1)*68+m] = v.y;
            As[(kv*4+2)*68+m] = v.z; As[(kv*4+3)*68+m] = v.w;
        }
        #pragma unroll
        for (int q = 0; q < 2; ++q) {
            int idx = q * 256 + tid;
            int n4 = idx & 15, kk = idx >> 4;
            int k = k0 + kk;
            const float* src = (k < EM + E) ? (p.W_ih + (size_t)k * 1024)
                                            : (p.W_hh + (size_t)(k - EM - E) * 1024);
            float4 v = *(const float4*)(src + cb * 64 + n4 * 4);
            *(float4*)&Bs[kk*64 + n4*4] = v;
        }
        __syncthreads();
        #pragma unroll
        for (int kk = 0; kk < 32; ++kk) {
            float4 av = *(const float4*)&As[kk*68 + ty*4];
            float4 bv = *(const float4*)&Bs[kk*64 + tx*4];
            acc[0][0] += av.x*bv.x; acc[0][1] += av.x*bv.y; acc[0][2] += av.x*bv.z; acc[0][3] += av.x*bv.w;
            acc[1][0] += av.y*bv.x; acc[1][1] += av.y*bv.y; acc[1][2] += av.y*bv.z; acc[1][3] += av.y*bv.w;
            acc[2][0] += av.z*bv.x; acc[2][1] += av.z*bv.y; acc[2][2] += av.z*bv.z; acc[2][3] += av.z*bv.w;
            acc[3][0] += av.w*bv.x; acc[3][1] += av.w*bv.y; acc[3][2] += av.w*bv.z; acc[3][3] += av.w*bv.w;
        }
        __syncthreads();
    }
    #pragma unroll
    for (int a = 0; a < 4; ++a) {
        int bidx = ty * 4 + a;
        float4 o = {acc[a][0], acc[a][1], acc[a][2], acc[a][3]};
        *(float4*)(p.gpart + ((size_t)ky * B + bidx) * 1024 + cb * 64 + tx * 4) = o;
    }
}

// ---------- head tile: 64 cols x 32 rows at step t (LDS: 8192 floats exactly) ----------
// hs[32][256], no pad: hot-loop reads are wave-broadcast (same addr across lanes).
__device__ __forceinline__ void head_tile(const Params& p, int t, int id, int tid, float* sm) {
    int cb = id % 157, qh = id / 157;
    if (p.target[qh * 32] <= t) return;   // sorted: whole tile inactive
    float* hs = sm;
    __syncthreads();
    #pragma unroll
    for (int q = 0; q < 8; ++q) {
        int idx = q * 256 + tid;
        int r = idx >> 6, kq = idx & 63;
        float4 v = *(const float4*)(p.hn_all + ((size_t)t * B + qh * 32 + r) * D + kq * 4);
        *(float4*)&hs[r * 256 + kq * 4] = v;
    }
    __syncthreads();
    int col = cb * 64 + (tid & 63);
    int rgrp = (tid >> 6) * 8;
    if (col < V) {
        float acc[8] = {};
        for (int kq = 0; kq < 64; ++kq) {
            float w0 = p.W_head[(size_t)(kq * 4 + 0) * V + col];
            float w1 = p.W_head[(size_t)(kq * 4 + 1) * V + col];
            float w2 = p.W_head[(size_t)(kq * 4 + 2) * V + col];
            float w3 = p.W_head[(size_t)(kq * 4 + 3) * V + col];
            #pragma unroll
            for (int r = 0; r < 8; ++r) {
                float4 hv = *(const float4*)&hs[(rgrp + r) * 256 + kq * 4];
                acc[r] += hv.x * w0 + hv.y * w1 + hv.z * w2 + hv.w * w3;
            }
        }
        float bh_ = p.b_head[col];
        #pragma unroll
        for (int r = 0; r < 8; ++r) {
            int brow = qh * 32 + rgrp + r;
            if (p.target[brow] > t)
                p.out1[((size_t)brow * T + t) * V + col] = acc[r] + bh_;
        }
    }
}

// ================= persistent megakernel =================
// LDS: 8192 floats = 32768 B exactly -> 2 blocks/CU within the 64 KB occupancy budget.
__global__ __launch_bounds__(256, 2) void mega(Params p) {
    cg::grid_group grid = cg::this_grid();
    __shared__ __align__(16) float sm[8192];
    int blk = blockIdx.x, tid = threadIdx.x;
    int G = gridDim.x;

    // P0: sort (block 0)
    if (blk == 0) {
        int* lens = (int*)sm;
        if (tid < B) lens[tid] = p.clen[tid];
        __syncthreads();
        if (tid < B) {
            int li = lens[tid], rank = 0;
            for (int j = 0; j < B; ++j) {
                int lj = lens[j];
                if (lj > li || (lj == li && j < tid)) rank++;
            }
            p.order[rank] = tid;
            p.target[rank] = li - 1;
        }
    }
    grid.sync();

    // P1: fe tiles (392) + mean (512), grid-strided
    for (int task = blk; task < 904; task += G) {
        if (task < 392) {
            fe_tile(p, task, tid, sm);
        } else {
            int mt = task - 392;
            int b = mt >> 3, e0 = (mt & 7) << 8;
            int src = p.order[b];
            const float* fp = p.feat + (size_t)src * P * E + e0 + tid;
            float acc = 0.f;
            #pragma unroll 4
            for (int pp = 0; pp < P; ++pp) acc += fp[(size_t)pp * E];
            p.mean_feat[b * E + e0 + tid] = acc * (1.0f / 196.0f);
        }
    }
    grid.sync();

    // P2: h0c0 split-K GEMM (64 tasks)
    for (int task = blk; task < 64; task += G) h0c0_tile(p, task, tid, sm);
    grid.sync();

    // P3: h0c0 reduce + xbuf init
    for (int task = blk; task < 64; task += G) reduce_task(p, task, tid);
    grid.sync();

    // recurrent loop
    for (int t = 0; t < T; ++t) {
        for (int task = blk; task < B; task += G) attn_pw_phase(p, t, task, tid, sm);
        grid.sync();
        for (int task = blk; task < 512; task += G) ctx_phase(p, t, task >> 3, task & 7, tid, sm);
        grid.sync();
        for (int task = blk; task < 442; task += G) {
            if (task < 128) lstm_tile(p, task & 15, task >> 4, tid, sm);
            else if (t >= 1) head_tile(p, t - 1, task - 128, tid, sm);
        }
        grid.sync();
    }
    // final pointwise (step T-1), then its head slice
    for (int task = blk; task < B; task += G) attn_pw_phase(p, T, task, tid, sm);
    grid.sync();
    for (int task = blk; task < 314; task += G) head_tile(p, T - 1, task, tid, sm);
}

extern "C" void kernel_launch(void* const* d_in, const int* in_sizes, int n_in,
                              void* d_out, int out_size, void* d_ws, size_t ws_size,
                              hipStream_t stream) {
    Params p;
    p.feat   = (const float*)d_in[0];
    p.tok    = (const int*)d_in[1];
    p.clen   = (const int*)d_in[2];
    p.Wf     = (const float*)d_in[3];
    p.bf     = (const float*)d_in[4];
    p.Wh     = (const float*)d_in[5];
    p.bh     = (const float*)d_in[6];
    p.We     = (const float*)d_in[7];
    p.be     = (const float*)d_in[8];
    p.emb    = (const float*)d_in[9];
    p.W_ih   = (const float*)d_in[10];
    p.b_ih   = (const float*)d_in[11];
    p.W_hh   = (const float*)d_in[12];
    p.b_hh   = (const float*)d_in[13];
    p.W_hid  = (const float*)d_in[14];
    p.b_hid  = (const float*)d_in[15];
    p.W_cell = (const float*)d_in[16];
    p.b_cell = (const float*)d_in[17];
    p.W_gate = (const float*)d_in[18];
    p.b_gate = (const float*)d_in[19];
    p.W_head = (const float*)d_in[20];
    p.b_head = (const float*)d_in[21];

    p.out1 = (float*)d_out;
    p.out2 = p.out1 + (size_t)B * T * V;

    char* wp = (char*)d_ws;
    p.order   = (int*)wp;            wp += 256;
    p.target  = (int*)wp;            wp += 256;
    p.fe      = (float*)wp;          wp += (size_t)B * P * H_ * sizeof(float);
    p.h       = (float*)wp;          wp += (size_t)B * D * sizeof(float);
    p.c       = (float*)wp;          wp += (size_t)B * D * sizeof(float);
    p.wbuf    = (float*)wp;          wp += (size_t)B * P * sizeof(float);
    p.xbuf    = (float*)wp;          wp += (size_t)B * KX * sizeof(float);
    p.gpart   = (float*)wp;          wp += (size_t)8 * B * 1024 * sizeof(float);
    p.mean_feat = (float*)wp;        wp += (size_t)B * E * sizeof(float);
    p.hpart   = (float*)wp;          wp += (size_t)8 * B * 512 * sizeof(float);
    p.hn_all  = (float*)wp;          wp += (size_t)T * B * D * sizeof(float);

    hipMemsetAsync(d_out, 0, (size_t)out_size * sizeof(float), stream);

    // Size the cooperative grid from what the runtime will actually allow.
    int dev = 0;
    hipGetDevice(&dev);
    int numCU = 256;
    hipDeviceGetAttribute(&numCU, hipDeviceAttributeMultiprocessorCount, dev);
    int maxBlocksPerCU = 0;
    hipOccupancyMaxActiveBlocksPerMultiprocessor(&maxBlocksPerCU, (const void*)mega, 256, 0);
    if (maxBlocksPerCU < 1) maxBlocksPerCU = 1;
    long long g = (long long)maxBlocksPerCU * (long long)numCU;
    if (g > 512) g = 512;
    if (g < 64) g = 64;

    void* kargs[] = { (void*)&p };
    hipLaunchCooperativeKernel((const void*)mega, dim3((unsigned)g), dim3(256), kargs, 0, stream);
}